// Round 6
// baseline (35924.841 us; speedup 1.0000x reference)
//
#include <hip/hip_runtime.h>

// BasicGRU persistent kernel for MI355X (gfx950) — round 6.
//
// WAVE-ACTOR dataflow, flag-gated (flags only — R4/R5's data-polling was
// metastable; R3's flag poll was stable). 64 wgs x 256 thr; wave w of wg b is
// a standalone actor: (group = w [16 batch rows], 16-col tile = b). Full
// K=768 per wave -> NO cross-wave reduce, NO __syncthreads in the loop.
//
//  roles: b<32: r-actor (r-gate cols [16b,+16)): poll h(t-1) -> GEMM(W1) ->
//         r=sigmoid -> hr=h*r store -> flag.
//         b>=32: z-actor (z-gate cols 512+16(b-32); u cols 16(b-32)):
//         poll h(t-1) -> GEMM(W1) -> zt in regs -> poll hr(t) -> GEMM(W2) ->
//         h(t) = lerp -> store -> flag. Own h cols stay in hnprev regs.
//  weights: hi bf16 in VGPRs (96/wave/matrix); lo bf16 in LDS, one shared
//         copy per wg (same tile for all 4 groups), cooperative preload.
//  exchange: u32 = (bf16hi<<16)|bf16lo, parity double-buffered; producer:
//         data stores -> s_waitcnt vmcnt(0) -> own flag (monotonic value t+1,
//         64B apart). consumer: 32-lane flag gather + __all, then 4-deep
//         pipelined chunk loads feeding 72 MFMA (3-product bf16 split).
//  WAR safety across parity reuse: transitively ordered through the
//         h->hr->h flag chain (any h(t) store follows full consumption of
//         h(t-2)/hr(t-2)).
//
// ws: h2 u32[2][64][512] @0; hr2 @262144; zflags @524288 (4 grp x 32 x 64B);
//     rflags @532480. total 540672 B, memset 0 (h(-1)=0, flags=0=ready@t=0).

#define TT 2048
#define DD 256
#define UU 512

typedef short bf16x8 __attribute__((ext_vector_type(8)));
typedef float f32x4 __attribute__((ext_vector_type(4)));
typedef unsigned int u32;
typedef unsigned long long u64;

#define H2_OFF 0
#define HR2_OFF 262144
#define ZF_OFF 524288
#define RF_OFF 532480
#define WS_BYTES 540672

__device__ inline unsigned short f2bf(float f) {
  unsigned u = __builtin_bit_cast(unsigned, f);
  u += 0x7FFFu + ((u >> 16) & 1u);  // round-nearest-even
  return (unsigned short)(u >> 16);
}
__device__ inline float bf2f(unsigned short b) {
  unsigned u = ((unsigned)b) << 16;
  return __builtin_bit_cast(float, u);
}
__device__ inline u32 ld_coh_u32(const u32* p) {
  return __hip_atomic_load(p, __ATOMIC_RELAXED, __HIP_MEMORY_SCOPE_AGENT);
}
__device__ inline u64 ld_coh_u64(const u64* p) {
  return __hip_atomic_load(p, __ATOMIC_RELAXED, __HIP_MEMORY_SCOPE_AGENT);
}
__device__ inline void st_coh_u32(u32* p, u32 v) {
  __hip_atomic_store(p, v, __ATOMIC_RELAXED, __HIP_MEMORY_SCOPE_AGENT);
}

#define MFMA(A, B, C) __builtin_amdgcn_mfma_f32_16x16x32_bf16((A), (B), (C), 0, 0, 0)

__global__ __launch_bounds__(256, 1) void gru_persist(
    const float* __restrict__ x, const float* __restrict__ Wk,
    const float* __restrict__ Wrk, const float* __restrict__ brk,
    const float* __restrict__ Wu, const float* __restrict__ Wur,
    const float* __restrict__ bur, float* __restrict__ out,
    unsigned char* __restrict__ ws) {
  // [w1hi | w1lo | w2hi | w2lo], each 12288 shorts (768 k x 16 cols). 96 KiB.
  __shared__ short wsh[49152];

  const int b = blockIdx.x;      // tile id 0..63
  const bool zrole = (b >= 32);
  const int tid = threadIdx.x;
  const int lane = tid & 63;
  const int g = tid >> 6;        // batch group 0..3 (= wave id)
  const int kgrp = lane >> 4;
  const int c = lane & 15;

  const int C1 = zrole ? 512 + (b - 32) * 16 : b * 16;  // phase-1 cols
  const int C2 = zrole ? (b - 32) * 16 : 0;             // phase-2 u cols

  // ---- cooperative one-time weight preload (hi+lo split into LDS).
  // layout addr(k,cc) = (k>>5)*512 + ((k>>3)&3)*128 + cc*8 + (k&7)
  for (int idx = tid; idx < 12288; idx += 256) {
    int k = idx >> 4, cc = idx & 15;
    int ad = (k >> 5) * 512 + ((k >> 3) & 3) * 128 + cc * 8 + (k & 7);
    float v = (k < DD) ? Wk[(size_t)k * 1024 + C1 + cc]
                       : Wrk[(size_t)(k - DD) * 1024 + C1 + cc];
    unsigned short hb = f2bf(v);
    wsh[ad] = (short)hb;
    wsh[12288 + ad] = (short)f2bf(v - bf2f(hb));
    if (zrole) {
      float v2 = (k < DD) ? Wu[(size_t)k * UU + C2 + cc]
                          : Wur[(size_t)(k - DD) * UU + C2 + cc];
      unsigned short hb2 = f2bf(v2);
      wsh[24576 + ad] = (short)hb2;
      wsh[36864 + ad] = (short)f2bf(v2 - bf2f(hb2));
    }
  }
  __syncthreads();

  // per-wave hi fragments -> VGPRs (lane reads its own (c,kgrp) slot)
  bf16x8 w1hi[24];
#pragma unroll
  for (int j = 0; j < 24; ++j)
    w1hi[j] = *(const bf16x8*)&wsh[j * 512 + lane * 8];
  bf16x8 w2hi[24];
  if (zrole) {
#pragma unroll
    for (int j = 0; j < 24; ++j)
      w2hi[j] = *(const bf16x8*)&wsh[24576 + j * 512 + lane * 8];
  }

  u32* h2p = (u32*)(ws + H2_OFF);
  u32* hr2p = (u32*)(ws + HR2_OFF);
  u32* zfg = (u32*)(ws + ZF_OFF) + g * 512;  // 32 flags x 16 u32 (64B) apart
  u32* rfg = (u32*)(ws + RF_OFF) + g * 512;
  const int ti = zrole ? b - 32 : b;
  u32* myflag = (zrole ? zfg : rfg) + ti * 16;

  const float b1 = brk[C1 + c];
  const float b2 = zrole ? bur[C2 + c] : 0.f;

  const float* xrow = x + (size_t)(16 * g + c) * TT * DD;  // A row for lane

  bf16x8 xhi[8], xlo[8];
  auto split_x = [&](int t) {
#pragma unroll
    for (int j = 0; j < 8; ++j) {
      const float* p = xrow + (size_t)t * DD + j * 32 + kgrp * 8;
      f32x4 v0 = *(const f32x4*)p;
      f32x4 v1 = *(const f32x4*)(p + 4);
#pragma unroll
      for (int i = 0; i < 4; ++i) {
        unsigned short hb = f2bf(v0[i]);
        xhi[j][i] = (short)hb;
        xlo[j][i] = (short)f2bf(v0[i] - bf2f(hb));
        unsigned short hb2 = f2bf(v1[i]);
        xhi[j][4 + i] = (short)hb2;
        xlo[j][4 + i] = (short)f2bf(v1[i] - bf2f(hb2));
      }
    }
  };

  auto waitflags = [&](const u32* f, u32 need) {
    const u32* p = f + (lane & 31) * 16;
    while (!__all(ld_coh_u32(p) >= need)) __builtin_amdgcn_s_sleep(1);
  };

  // full-K GEMM for one 16x16 tile: x chunks (regs) + 16 packed-h chunks
  // (coherent, 4-deep pipelined loads), 3-product bf16-split MFMA, 4 accs.
  auto gemm768 = [&](const u32* rowbase, const bf16x8* whi,
                     int loreg) -> f32x4 {
    f32x4 ac0 = {0.f, 0.f, 0.f, 0.f}, ac1 = ac0, ac2 = ac0, ac3 = ac0;
#pragma unroll
    for (int j = 0; j < 8; ++j) {
      bf16x8 blo = *(const bf16x8*)&wsh[loreg + j * 512 + lane * 8];
      f32x4& a = (j & 3) == 0 ? ac0 : ((j & 3) == 1 ? ac1 : ((j & 3) == 2 ? ac2 : ac3));
      a = MFMA(xhi[j], whi[j], a);
      a = MFMA(xhi[j], blo, a);
      a = MFMA(xlo[j], whi[j], a);
    }
    u64 Q[4][4];
#pragma unroll
    for (int p = 0; p < 4; ++p) {
      const u64* s = (const u64*)(rowbase + p * 32 + kgrp * 8);
      Q[p][0] = ld_coh_u64(s + 0); Q[p][1] = ld_coh_u64(s + 1);
      Q[p][2] = ld_coh_u64(s + 2); Q[p][3] = ld_coh_u64(s + 3);
    }
#pragma unroll
    for (int j = 0; j < 16; ++j) {
      bf16x8 ahi, alo;
#pragma unroll
      for (int i = 0; i < 4; ++i) {
        u32 lo32 = (u32)Q[j & 3][i], hi32 = (u32)(Q[j & 3][i] >> 32);
        ahi[2 * i] = (short)(lo32 >> 16);
        alo[2 * i] = (short)lo32;
        ahi[2 * i + 1] = (short)(hi32 >> 16);
        alo[2 * i + 1] = (short)hi32;
      }
      if (j + 4 < 16) {
        const u64* s = (const u64*)(rowbase + (j + 4) * 32 + kgrp * 8);
        Q[j & 3][0] = ld_coh_u64(s + 0); Q[j & 3][1] = ld_coh_u64(s + 1);
        Q[j & 3][2] = ld_coh_u64(s + 2); Q[j & 3][3] = ld_coh_u64(s + 3);
      }
      bf16x8 blo = *(const bf16x8*)&wsh[loreg + (8 + j) * 512 + lane * 8];
      f32x4& a = (j & 3) == 0 ? ac0 : ((j & 3) == 1 ? ac1 : ((j & 3) == 2 ? ac2 : ac3));
      a = MFMA(ahi, whi[8 + j], a);
      a = MFMA(ahi, blo, a);
      a = MFMA(alo, whi[8 + j], a);
    }
    return (ac0 + ac1) + (ac2 + ac3);
  };

  split_x(0);
  float hnprev[4] = {0.f, 0.f, 0.f, 0.f};  // z-actor's own h cols (C layout)

  for (int t = 0; t < TT; ++t) {
    const int bh = (t + 1) & 1;  // parity buffer holding h(t-1)

    // ---- phase 1: wait h(t-1), GEMM W1
    waitflags(zfg, (u32)t);
    u32 oh0 = 0, oh1 = 0, oh2 = 0, oh3 = 0;
    if (!zrole) {  // prefetch own h(t-1) elems (row 4*(lane>>4)+ri, col C1+c)
      const u32* q =
          h2p + ((size_t)(bh * 64 + 16 * g + 4 * (lane >> 4))) * 512 + C1 + c;
      oh0 = ld_coh_u32(q);       oh1 = ld_coh_u32(q + 512);
      oh2 = ld_coh_u32(q + 1024); oh3 = ld_coh_u32(q + 1536);
    }
    const u32* hrow = h2p + ((size_t)(bh * 64 + 16 * g + c)) * 512;
    f32x4 acc = gemm768(hrow, w1hi, 12288);
    float s0 = 1.f / (1.f + __expf(-(acc[0] + b1)));
    float s1 = 1.f / (1.f + __expf(-(acc[1] + b1)));
    float s2 = 1.f / (1.f + __expf(-(acc[2] + b1)));
    float s3 = 1.f / (1.f + __expf(-(acc[3] + b1)));

    if (!zrole) {
      // r gate: hr = h * r, pack and store, flag.
      u32* dst =
          hr2p + ((size_t)((t & 1) * 64 + 16 * g + 4 * (lane >> 4))) * 512 +
          C1 + c;
      u32 ohs[4] = {oh0, oh1, oh2, oh3};
      float ss[4] = {s0, s1, s2, s3};
#pragma unroll
      for (int ri = 0; ri < 4; ++ri) {
        float h = bf2f((unsigned short)(ohs[ri] >> 16)) +
                  bf2f((unsigned short)ohs[ri]);
        float hrv = h * ss[ri];
        unsigned short hb = f2bf(hrv);
        unsigned short lb = f2bf(hrv - bf2f(hb));
        st_coh_u32(dst + ri * 512, ((u32)hb << 16) | lb);
      }
      asm volatile("s_waitcnt vmcnt(0)" ::: "memory");
      if (lane == 0) st_coh_u32(myflag, (u32)(t + 1));
      if (t + 1 < TT) split_x(t + 1);
    } else {
      // ---- phase 2: zt in regs; wait hr(t), GEMM W2, h update.
      waitflags(rfg, (u32)(t + 1));
      const u32* hrrow = hr2p + ((size_t)((t & 1) * 64 + 16 * g + c)) * 512;
      f32x4 uacc = gemm768(hrrow, w2hi, 36864);
      u32* dst =
          h2p + ((size_t)((t & 1) * 64 + 16 * g + 4 * (lane >> 4))) * 512 +
          C2 + c;
      float zz[4] = {s0, s1, s2, s3};
#pragma unroll
      for (int ri = 0; ri < 4; ++ri) {
        float uv = uacc[ri] + b2;
        float e = __expf(2.f * uv);
        float ht = 1.f - 2.f / (e + 1.f);  // tanh
        float hn = hnprev[ri] + zz[ri] * (ht - hnprev[ri]);
        hnprev[ri] = hn;
        unsigned short hb = f2bf(hn);
        unsigned short lb = f2bf(hn - bf2f(hb));
        st_coh_u32(dst + ri * 512, ((u32)hb << 16) | lb);
        if (t == TT - 1)
          out[(size_t)(16 * g + 4 * (lane >> 4) + ri) * UU + C2 + c] = hn;
      }
      asm volatile("s_waitcnt vmcnt(0)" ::: "memory");
      if (lane == 0) st_coh_u32(myflag, (u32)(t + 1));
      if (t + 1 < TT) split_x(t + 1);
    }
  }
}

extern "C" void kernel_launch(void* const* d_in, const int* in_sizes, int n_in,
                              void* d_out, int out_size, void* d_ws,
                              size_t ws_size, hipStream_t stream) {
  (void)in_sizes; (void)n_in; (void)out_size; (void)ws_size;
  hipMemsetAsync(d_ws, 0, WS_BYTES, stream);  // h(-1)=0, flags=0 (ready @ t=0)
  gru_persist<<<dim3(64), dim3(256), 0, stream>>>(
      (const float*)d_in[0], (const float*)d_in[1], (const float*)d_in[2],
      (const float*)d_in[3], (const float*)d_in[4], (const float*)d_in[5],
      (const float*)d_in[6], (float*)d_out, (unsigned char*)d_ws);
}

// Round 8
// 14567.169 us; speedup vs baseline: 2.4662x; 2.4662x over previous
//
#include <hip/hip_runtime.h>

// BasicGRU persistent kernel for MI355X (gfx950) — round 8.
//
// SAFE agent-scope dataflow (all primitives proven in R2-R6; no XCD/scope
// assumptions after R7's deadlock). 256 wgs x 256 thr, 1 wg/CU (83KB LDS).
//
//  - 8 groups (g = blockIdx&7) x 32 wgs (rank = blockIdx>>3), 8 batch rows
//    per group. MERGED roles: each wg does r-tile cols [16r,+16) AND z-tile
//    cols 512+[16r,+16) in phase 1 (shared A-fragments), u-tile cols
//    [16r,+16) in phase 2. zt-gate and own-h element stay in registers.
//  - exchange: h/hr packed u32 (bf16hi<<16|lo), parity double-buffered,
//    relaxed agent-scope (sc0 sc1) loads/stores. Producer: data stores ->
//    s_waitcnt vmcnt(0) -> per-WAVE flag (waves 0,1 = the storing waves;
//    monotonic value 2t+1 / 2t+2, 64B apart). Consumer: single 64-lane
//    gather over the group's 64 flag slots + __all, s_sleep(1) backoff.
//  - post-poll path is minimal: 16 coherent u64 chunk loads (batched) ->
//    unpack -> 24 MFMAs -> LDS reduce. x-only MFMAs and split_x(t+1) run
//    BEFORE the polls (hidden in the wait).
//  - WAR on parity buffers: transitive through the flag chain (R3/R6 arg).
//  - weights: hi bf16 in VGPRs (72/wave: r,z,u x 6 chunks), lo bf16 in LDS
//    (3 tiles x 768 x 16 = 73.7KB); 3-product bf16-split MFMA (~1.5e-5 rel).
//
// ws: h2 u32[2][64][512] @0 (256KB); hr2 @262144 (256KB);
//     flags @524288: 8 groups x 64 slots x 64B (32KB). total 557056, memset 0
//     each launch (h(-1)=0, flags=0 == ready @ t=0).

#define TT 2048
#define DD 256
#define UU 512

typedef short bf16x8 __attribute__((ext_vector_type(8)));
typedef float f32x4 __attribute__((ext_vector_type(4)));
typedef unsigned int u32;
typedef unsigned long long u64;

#define H2_OFF 0
#define HR2_OFF 262144
#define FLAG_OFF 524288
#define WS_BYTES 557056

__device__ inline unsigned short f2bf(float f) {
  unsigned u = __builtin_bit_cast(unsigned, f);
  u += 0x7FFFu + ((u >> 16) & 1u);  // round-nearest-even
  return (unsigned short)(u >> 16);
}
__device__ inline float bf2f(unsigned short b) {
  unsigned u = ((unsigned)b) << 16;
  return __builtin_bit_cast(float, u);
}
__device__ inline u32 ld_coh_u32(const u32* p) {
  return __hip_atomic_load(p, __ATOMIC_RELAXED, __HIP_MEMORY_SCOPE_AGENT);
}
__device__ inline u64 ld_coh_u64(const u64* p) {
  return __hip_atomic_load(p, __ATOMIC_RELAXED, __HIP_MEMORY_SCOPE_AGENT);
}
__device__ inline void st_coh_u32(u32* p, u32 v) {
  __hip_atomic_store(p, v, __ATOMIC_RELAXED, __HIP_MEMORY_SCOPE_AGENT);
}

#define MFMA(A, B, C) __builtin_amdgcn_mfma_f32_16x16x32_bf16((A), (B), (C), 0, 0, 0)

__global__ __launch_bounds__(256, 1) void gru_persist(
    const float* __restrict__ x, const float* __restrict__ Wk,
    const float* __restrict__ Wrk, const float* __restrict__ brk,
    const float* __restrict__ Wu, const float* __restrict__ Wur,
    const float* __restrict__ bur, float* __restrict__ out,
    unsigned char* __restrict__ ws) {
  __shared__ short wlo[36864];    // lo weights [3 tiles][24 ch][64 lane][8]
  __shared__ float scratch[2304]; // ph1: r@0 z@1024; ph2: u@0 (+pad -> 83KB)

  const int wgid = blockIdx.x;
  const int g = wgid & 7;         // group (8 batch rows [8g,8g+8))
  const int rank = wgid >> 3;     // 0..31 -> 16-col tile
  const int tid = threadIdx.x;
  const int lane = tid & 63;
  const int wv = tid >> 6;
  const int kgrp = lane >> 4;
  const int c = lane & 15;

  const int C1 = 16 * rank;       // r-gate / u cols
  const int C1z = 512 + C1;       // z-gate cols

  // ---- one-time: hi weight fragments -> VGPRs
  bf16x8 wrhi[6], wzhi[6], wuhi[6];
#pragma unroll
  for (int j = 0; j < 6; ++j) {
    const int kb = 32 * (wv + 4 * j) + kgrp * 8;
#pragma unroll
    for (int i = 0; i < 8; ++i) {
      const int k = kb + i;
      float vr = (k < DD) ? Wk[(size_t)k * 1024 + C1 + c]
                          : Wrk[(size_t)(k - DD) * 1024 + C1 + c];
      float vz = (k < DD) ? Wk[(size_t)k * 1024 + C1z + c]
                          : Wrk[(size_t)(k - DD) * 1024 + C1z + c];
      float vu = (k < DD) ? Wu[(size_t)k * UU + C1 + c]
                          : Wur[(size_t)(k - DD) * UU + C1 + c];
      wrhi[j][i] = (short)f2bf(vr);
      wzhi[j][i] = (short)f2bf(vz);
      wuhi[j][i] = (short)f2bf(vu);
    }
  }
  // ---- one-time: lo weights -> LDS (cooperative; T0=r, T1=z, T2=u)
  for (int idx = tid; idx < 3 * 12288; idx += 256) {
    const int T = idx / 12288;
    const int rem = idx - T * 12288;
    const int k = rem >> 4, cc = rem & 15;
    float v;
    if (T == 0)
      v = (k < DD) ? Wk[(size_t)k * 1024 + C1 + cc]
                   : Wrk[(size_t)(k - DD) * 1024 + C1 + cc];
    else if (T == 1)
      v = (k < DD) ? Wk[(size_t)k * 1024 + C1z + cc]
                   : Wrk[(size_t)(k - DD) * 1024 + C1z + cc];
    else
      v = (k < DD) ? Wu[(size_t)k * UU + C1 + cc]
                   : Wur[(size_t)(k - DD) * UU + C1 + cc];
    unsigned short hb = f2bf(v);
    const int ch = k >> 5, kk = k & 31;
    wlo[((T * 24 + ch) * 64 + (kk >> 3) * 16 + cc) * 8 + (kk & 7)] =
        (short)f2bf(v - bf2f(hb));
  }
  __syncthreads();

  u32* h2 = (u32*)(ws + H2_OFF);    // [2][64 rows][512]
  u32* hr2 = (u32*)(ws + HR2_OFF);  // [2][64 rows][512]
  u32* flg = (u32*)(ws + FLAG_OFF) + (size_t)g * 1024;  // 64 slots x 16 u32
  u32* myflag = flg + (rank * 2 + wv) * 16;             // used by wv<2 only

  const int bl = tid >> 4, cl = tid & 15;  // reduce coords (bl<8 meaningful)
  const float b_r = brk[C1 + cl];
  const float b_z = brk[C1z + cl];
  const float b_u = bur[C1 + cl];

  const int arow = c & 7;  // A rows 8..15 duplicate 0..7 (C rows 8..15 unused)
  const float* xrow = x + (size_t)(8 * g + arow) * TT * DD;

  bf16x8 xhi[2], xlo[2];
  auto split_x = [&](int t) {
#pragma unroll
    for (int j = 0; j < 2; ++j) {
      const float* p = xrow + (size_t)t * DD + 32 * wv + 128 * j + kgrp * 8;
      f32x4 v0 = *(const f32x4*)p;
      f32x4 v1 = *(const f32x4*)(p + 4);
#pragma unroll
      for (int i = 0; i < 4; ++i) {
        unsigned short hb = f2bf(v0[i]);
        xhi[j][i] = (short)hb;
        xlo[j][i] = (short)f2bf(v0[i] - bf2f(hb));
        unsigned short hb2 = f2bf(v1[i]);
        xhi[j][4 + i] = (short)hb2;
        xlo[j][4 + i] = (short)f2bf(v1[i] - bf2f(hb2));
      }
    }
  };

  auto poll = [&](u32 need) {  // all 64 slots of the group >= need
    const u32* p = flg + lane * 16;
    while (!__all(ld_coh_u32(p) >= need)) __builtin_amdgcn_s_sleep(1);
  };

  auto chunk3 = [&](const bf16x8& ahi, const bf16x8& alo, const bf16x8& bhi,
                    const bf16x8& blo, f32x4& acc) {
    acc = MFMA(ahi, bhi, acc);
    acc = MFMA(ahi, blo, acc);
    acc = MFMA(alo, bhi, acc);
  };

  split_x(0);
  float hown = 0.f, zt_reg = 0.f;  // own h / update gate (threads tid<128)
  f32x4 ar = {0.f, 0.f, 0.f, 0.f}, az = ar;
#pragma unroll
  for (int j = 0; j < 2; ++j) {  // t=0 x-partials
    bf16x8 br = *(const bf16x8*)&wlo[((wv + 4 * j) * 64 + lane) * 8];
    bf16x8 bz = *(const bf16x8*)&wlo[((24 + wv + 4 * j) * 64 + lane) * 8];
    chunk3(xhi[0 + j], xlo[0 + j], wrhi[j], br, ar);
    chunk3(xhi[0 + j], xlo[0 + j], wzhi[j], bz, az);
  }

  for (int t = 0; t < TT; ++t) {
    // ================= phase 1: wait h(t-1); r+z h-part GEMM
    poll(2 * (u32)t);
    {
      const int bh = (t + 1) & 1;
      const u64* hb = (const u64*)(h2 + ((size_t)(bh * 64 + 8 * g + arow)) * 512 +
                                   32 * wv + kgrp * 8);
      u64 Q[16];
#pragma unroll
      for (int p = 0; p < 4; ++p) {
        Q[4 * p + 0] = ld_coh_u64(hb + 64 * p + 0);
        Q[4 * p + 1] = ld_coh_u64(hb + 64 * p + 1);
        Q[4 * p + 2] = ld_coh_u64(hb + 64 * p + 2);
        Q[4 * p + 3] = ld_coh_u64(hb + 64 * p + 3);
      }
#pragma unroll
      for (int p = 0; p < 4; ++p) {
        bf16x8 ahi, alo;
#pragma unroll
        for (int i = 0; i < 4; ++i) {
          u32 lo32 = (u32)Q[4 * p + i], hi32 = (u32)(Q[4 * p + i] >> 32);
          ahi[2 * i] = (short)(lo32 >> 16);
          alo[2 * i] = (short)lo32;
          ahi[2 * i + 1] = (short)(hi32 >> 16);
          alo[2 * i + 1] = (short)hi32;
        }
        const int j = p + 2;
        bf16x8 br = *(const bf16x8*)&wlo[((wv + 4 * j) * 64 + lane) * 8];
        bf16x8 bz = *(const bf16x8*)&wlo[((24 + wv + 4 * j) * 64 + lane) * 8];
        chunk3(ahi, alo, wrhi[j], br, ar);
        chunk3(ahi, alo, wzhi[j], bz, az);
      }
    }
    __syncthreads();  // WAR: prev phase-2 reduce reads done
#pragma unroll
    for (int r = 0; r < 4; ++r) {
      scratch[wv * 256 + (kgrp * 4 + r) * 16 + c] = ar[r];
      scratch[1024 + wv * 256 + (kgrp * 4 + r) * 16 + c] = az[r];
    }
    __syncthreads();
    if (tid < 128) {
      float rv = (scratch[tid] + scratch[256 + tid]) +
                 (scratch[512 + tid] + scratch[768 + tid]) + b_r;
      float zv = (scratch[1024 + tid] + scratch[1280 + tid]) +
                 (scratch[1536 + tid] + scratch[1792 + tid]) + b_z;
      float rg = 1.f / (1.f + __expf(-rv));
      zt_reg = 1.f / (1.f + __expf(-zv));
      float hrv = hown * rg;
      unsigned short hb = f2bf(hrv);
      unsigned short lb = f2bf(hrv - bf2f(hb));
      st_coh_u32(hr2 + ((size_t)((t & 1) * 64 + 8 * g + bl)) * 512 + C1 + cl,
                 ((u32)hb << 16) | lb);
    }
    asm volatile("s_waitcnt vmcnt(0)" ::: "memory");
    if (wv < 2 && lane == 0) st_coh_u32(myflag, 2 * (u32)t + 1);

    // ================= phase 2: xu pre-GEMM + x(t+1) split (hidden), then hr
    f32x4 au = {0.f, 0.f, 0.f, 0.f};
#pragma unroll
    for (int j = 0; j < 2; ++j) {
      bf16x8 bu = *(const bf16x8*)&wlo[((48 + wv + 4 * j) * 64 + lane) * 8];
      chunk3(xhi[j], xlo[j], wuhi[j], bu, au);
    }
    if (t + 1 < TT) split_x(t + 1);
    poll(2 * (u32)t + 1);
    {
      const u64* hrb = (const u64*)(hr2 + ((size_t)((t & 1) * 64 + 8 * g + arow)) * 512 +
                                    32 * wv + kgrp * 8);
      u64 Q[16];
#pragma unroll
      for (int p = 0; p < 4; ++p) {
        Q[4 * p + 0] = ld_coh_u64(hrb + 64 * p + 0);
        Q[4 * p + 1] = ld_coh_u64(hrb + 64 * p + 1);
        Q[4 * p + 2] = ld_coh_u64(hrb + 64 * p + 2);
        Q[4 * p + 3] = ld_coh_u64(hrb + 64 * p + 3);
      }
#pragma unroll
      for (int p = 0; p < 4; ++p) {
        bf16x8 ahi, alo;
#pragma unroll
        for (int i = 0; i < 4; ++i) {
          u32 lo32 = (u32)Q[4 * p + i], hi32 = (u32)(Q[4 * p + i] >> 32);
          ahi[2 * i] = (short)(lo32 >> 16);
          alo[2 * i] = (short)lo32;
          ahi[2 * i + 1] = (short)(hi32 >> 16);
          alo[2 * i + 1] = (short)hi32;
        }
        const int j = p + 2;
        bf16x8 bu = *(const bf16x8*)&wlo[((48 + wv + 4 * j) * 64 + lane) * 8];
        chunk3(ahi, alo, wuhi[j], bu, au);
      }
    }
    __syncthreads();  // WAR: phase-1 reduce reads done
#pragma unroll
    for (int r = 0; r < 4; ++r)
      scratch[wv * 256 + (kgrp * 4 + r) * 16 + c] = au[r];
    __syncthreads();
    if (tid < 128) {
      float uv = (scratch[tid] + scratch[256 + tid]) +
                 (scratch[512 + tid] + scratch[768 + tid]) + b_u;
      float e = __expf(2.f * uv);
      float th = 1.f - 2.f / (e + 1.f);  // tanh(uv)
      float hn = hown + zt_reg * (th - hown);
      hown = hn;
      unsigned short hb = f2bf(hn);
      unsigned short lb = f2bf(hn - bf2f(hb));
      st_coh_u32(h2 + ((size_t)((t & 1) * 64 + 8 * g + bl)) * 512 + C1 + cl,
                 ((u32)hb << 16) | lb);
      if (t == TT - 1) out[(size_t)(8 * g + bl) * UU + C1 + cl] = hn;
    }
    asm volatile("s_waitcnt vmcnt(0)" ::: "memory");
    if (wv < 2 && lane == 0) st_coh_u32(myflag, 2 * (u32)t + 2);

    // ---- next-step phase-1 x-partials (hidden before next poll)
    ar = (f32x4){0.f, 0.f, 0.f, 0.f};
    az = (f32x4){0.f, 0.f, 0.f, 0.f};
    if (t + 1 < TT) {
#pragma unroll
      for (int j = 0; j < 2; ++j) {
        bf16x8 br = *(const bf16x8*)&wlo[((wv + 4 * j) * 64 + lane) * 8];
        bf16x8 bz = *(const bf16x8*)&wlo[((24 + wv + 4 * j) * 64 + lane) * 8];
        chunk3(xhi[j], xlo[j], wrhi[j], br, ar);
        chunk3(xhi[j], xlo[j], wzhi[j], bz, az);
      }
    }
  }
}

extern "C" void kernel_launch(void* const* d_in, const int* in_sizes, int n_in,
                              void* d_out, int out_size, void* d_ws,
                              size_t ws_size, hipStream_t stream) {
  (void)in_sizes; (void)n_in; (void)out_size; (void)ws_size;
  hipMemsetAsync(d_ws, 0, WS_BYTES, stream);  // h(-1)=0, flags=0 (ready @ t=0)
  gru_persist<<<dim3(256), dim3(256), 0, stream>>>(
      (const float*)d_in[0], (const float*)d_in[1], (const float*)d_in[2],
      (const float*)d_in[3], (const float*)d_in[4], (const float*)d_in[5],
      (const float*)d_in[6], (float*)d_out, (unsigned char*)d_ws);
}